// Round 2
// baseline (227.686 us; speedup 1.0000x reference)
//
#include <hip/hip_runtime.h>
#include <math.h>

// Problem constants (from reference): B=8, S=4096, D=1024, H=12.
#define D_DIM 1024
#define S_DIM 4096
#define F4_PER_ROW (D_DIM / 4)     // 256 float4 per (b,t) row
#define RPB 16                     // rows per block (16 outstanding 16B ld/st per thread)

#define TWO_PI     6.283185307179586476925286766559
#define INV_TWO_PI 0.159154943091895335768883763373

// Native clang vector type — required by __builtin_nontemporal_load/store.
typedef float vfloat4 __attribute__((ext_vector_type(4)));

// ---------------------------------------------------------------------------
// Fused kernel: each block owns RPB consecutive (b,t) rows x 1024 floats.
//  - Issue all RPB streaming nontemporal loads first (all in flight ~900cy).
//  - Lanes 0..RPB-1 of each wave compute wave[t] for the block's rows using
//    the EXACT same DP formula + accumulation order as the verified wave
//    kernel (numerics unchanged). Hidden under the load latency.
//  - Broadcast via __shfl (no LDS, no __syncthreads -> no vmcnt(0) drain
//    barrier between loads and stores).
// ---------------------------------------------------------------------------
__global__ void __launch_bounds__(256)
ResonanceField_fused16_kernel(const vfloat4* __restrict__ x,
                              const float* __restrict__ freq,
                              const float* __restrict__ amp,
                              const float* __restrict__ time_p,
                              vfloat4* __restrict__ out,
                              int H) {
    const int row0 = blockIdx.x * RPB;
    const int tid  = threadIdx.x;
    const size_t base = (size_t)row0 * F4_PER_ROW + tid;

    // 1) put all RPB row loads in flight before any compute
    vfloat4 v[RPB];
#pragma unroll
    for (int r = 0; r < RPB; ++r)
        v[r] = __builtin_nontemporal_load(&x[base + (size_t)r * F4_PER_ROW]);

    // 2) lanes 0..RPB-1 (per wave) compute the wave values; DP phase + cheap
    //    DP range reduction + fp32 sinf — identical numerics to the verified
    //    version. Redundant across the block's 4 waves but fully hidden
    //    (~3% of per-block memory time).
    const int lane = tid & 63;
    float wf = 0.0f;
    if (lane < RPB) {
        const int t = (row0 + lane) & (S_DIM - 1);
        const double tf = (double)time_p[0] + (double)t * (1.0 / (double)S_DIM);
        double acc = 0.0;
        for (int i = 0; i < H; ++i) {
            double ph = TWO_PI * (double)freq[i] * tf;
            double rr = ph - TWO_PI * rint(ph * INV_TWO_PI);   // |rr| <= pi
            acc += (double)amp[i] * (double)sinf((float)rr);
        }
        wf = (float)(acc / (double)H);
    }

    // 3) broadcast wave values across the wave
    float w[RPB];
#pragma unroll
    for (int r = 0; r < RPB; ++r)
        w[r] = __shfl(wf, r);

    // 4) scale + streaming store (stores retire in load-completion order)
#pragma unroll
    for (int r = 0; r < RPB; ++r) {
        vfloat4 t = v[r];
        t *= w[r];
        __builtin_nontemporal_store(t, &out[base + (size_t)r * F4_PER_ROW]);
    }
}

// ---------------------------------------------------------------------------
// Generic fallback: one (b,t) row per block (any row count). Same math.
// ---------------------------------------------------------------------------
__global__ void ResonanceField_fused1_kernel(const vfloat4* __restrict__ x,
                                             const float* __restrict__ freq,
                                             const float* __restrict__ amp,
                                             const float* __restrict__ time_p,
                                             vfloat4* __restrict__ out,
                                             int H) {
    const int t = blockIdx.x & (S_DIM - 1);
    const double tf = (double)time_p[0] + (double)t * (1.0 / (double)S_DIM);
    double acc = 0.0;
    for (int i = 0; i < H; ++i) {
        double ph = TWO_PI * (double)freq[i] * tf;
        double rr = ph - TWO_PI * rint(ph * INV_TWO_PI);
        acc += (double)amp[i] * (double)sinf((float)rr);
    }
    const float w = (float)(acc / (double)H);
    const size_t idx = (size_t)blockIdx.x * blockDim.x + threadIdx.x;
    vfloat4 v = x[idx];
    v *= w;
    out[idx] = v;
}

extern "C" void kernel_launch(void* const* d_in, const int* in_sizes, int n_in,
                              void* d_out, int out_size, void* d_ws, size_t ws_size,
                              hipStream_t stream) {
    const float* x      = (const float*)d_in[0];
    const float* freq   = (const float*)d_in[1];
    const float* amp    = (const float*)d_in[2];
    const float* time_p = (const float*)d_in[3];
    float* out = (float*)d_out;

    const int H = in_sizes[1];                        // 12
    const long long total = (long long)in_sizes[0];   // B*S*D = 33554432
    const int rows = (int)(total / D_DIM);            // B*S = 32768 rows
    const int threads = 256;                          // == F4_PER_ROW

    if ((rows % RPB) == 0) {
        ResonanceField_fused16_kernel<<<rows / RPB, threads, 0, stream>>>(
            (const vfloat4*)x, freq, amp, time_p, (vfloat4*)out, H);
    } else {
        ResonanceField_fused1_kernel<<<rows, threads, 0, stream>>>(
            (const vfloat4*)x, freq, amp, time_p, (vfloat4*)out, H);
    }
}

// Round 4
// 225.231 us; speedup vs baseline: 1.0109x; 1.0109x over previous
//
#include <hip/hip_runtime.h>
#include <math.h>

// Problem constants (from reference): B=8, S=4096, D=1024, H=12.
#define D_DIM 1024
#define S_DIM 4096
#define F4_PER_ROW (D_DIM / 4)     // 256 float4 per (b,t) row
#define RPB 8                      // rows per block — measured best (R1: 225.7us;
                                   // RPB=16 regressed to 227.7us: no MLP gain,
                                   // more VGPR pressure)

#define TWO_PI     6.283185307179586476925286766559
#define INV_TWO_PI 0.159154943091895335768883763373

// Native clang vector type — required by __builtin_nontemporal_load/store.
typedef float vfloat4 __attribute__((ext_vector_type(4)));

// ---------------------------------------------------------------------------
// Fused kernel: each block owns RPB consecutive (b,t) rows x 1024 floats.
//  - Issue all RPB streaming nontemporal loads first (all in flight ~900cy).
//  - Lanes 0..RPB-1 of each wave compute wave[t] for the block's rows using
//    the EXACT same DP formula + accumulation order as the verified wave
//    kernel (numerics unchanged). Hidden under the load latency.
//  - Broadcast via __shfl (no LDS, no __syncthreads -> no vmcnt(0) drain
//    barrier between loads and stores).
// ---------------------------------------------------------------------------
__global__ void __launch_bounds__(256)
ResonanceField_fused8_kernel(const vfloat4* __restrict__ x,
                             const float* __restrict__ freq,
                             const float* __restrict__ amp,
                             const float* __restrict__ time_p,
                             vfloat4* __restrict__ out,
                             int H) {
    const int row0 = blockIdx.x * RPB;
    const int tid  = threadIdx.x;
    const size_t base = (size_t)row0 * F4_PER_ROW + tid;

    // 1) put all RPB row loads in flight before any compute
    vfloat4 v[RPB];
#pragma unroll
    for (int r = 0; r < RPB; ++r)
        v[r] = __builtin_nontemporal_load(&x[base + (size_t)r * F4_PER_ROW]);

    // 2) lanes 0..RPB-1 (per wave) compute the wave values; DP phase + cheap
    //    DP range reduction + fp32 sinf — identical numerics to the verified
    //    version. Redundant across the block's 4 waves but fully hidden.
    const int lane = tid & 63;
    float wf = 0.0f;
    if (lane < RPB) {
        const int t = (row0 + lane) & (S_DIM - 1);
        const double tf = (double)time_p[0] + (double)t * (1.0 / (double)S_DIM);
        double acc = 0.0;
        for (int i = 0; i < H; ++i) {
            double ph = TWO_PI * (double)freq[i] * tf;
            double rr = ph - TWO_PI * rint(ph * INV_TWO_PI);   // |rr| <= pi
            acc += (double)amp[i] * (double)sinf((float)rr);
        }
        wf = (float)(acc / (double)H);
    }

    // 3) broadcast wave values across the wave
    float w[RPB];
#pragma unroll
    for (int r = 0; r < RPB; ++r)
        w[r] = __shfl(wf, r);

    // 4) scale + streaming store
#pragma unroll
    for (int r = 0; r < RPB; ++r) {
        vfloat4 t = v[r];
        t *= w[r];
        __builtin_nontemporal_store(t, &out[base + (size_t)r * F4_PER_ROW]);
    }
}

// ---------------------------------------------------------------------------
// Generic fallback: one (b,t) row per block (any row count). Same math.
// ---------------------------------------------------------------------------
__global__ void ResonanceField_fused1_kernel(const vfloat4* __restrict__ x,
                                             const float* __restrict__ freq,
                                             const float* __restrict__ amp,
                                             const float* __restrict__ time_p,
                                             vfloat4* __restrict__ out,
                                             int H) {
    const int t = blockIdx.x & (S_DIM - 1);
    const double tf = (double)time_p[0] + (double)t * (1.0 / (double)S_DIM);
    double acc = 0.0;
    for (int i = 0; i < H; ++i) {
        double ph = TWO_PI * (double)freq[i] * tf;
        double rr = ph - TWO_PI * rint(ph * INV_TWO_PI);
        acc += (double)amp[i] * (double)sinf((float)rr);
    }
    const float w = (float)(acc / (double)H);
    const size_t idx = (size_t)blockIdx.x * blockDim.x + threadIdx.x;
    vfloat4 v = x[idx];
    v *= w;
    out[idx] = v;
}

extern "C" void kernel_launch(void* const* d_in, const int* in_sizes, int n_in,
                              void* d_out, int out_size, void* d_ws, size_t ws_size,
                              hipStream_t stream) {
    const float* x      = (const float*)d_in[0];
    const float* freq   = (const float*)d_in[1];
    const float* amp    = (const float*)d_in[2];
    const float* time_p = (const float*)d_in[3];
    float* out = (float*)d_out;

    const int H = in_sizes[1];                        // 12
    const long long total = (long long)in_sizes[0];   // B*S*D = 33554432
    const int rows = (int)(total / D_DIM);            // B*S = 32768 rows
    const int threads = 256;                          // == F4_PER_ROW

    if ((rows % RPB) == 0) {
        ResonanceField_fused8_kernel<<<rows / RPB, threads, 0, stream>>>(
            (const vfloat4*)x, freq, amp, time_p, (vfloat4*)out, H);
    } else {
        ResonanceField_fused1_kernel<<<rows, threads, 0, stream>>>(
            (const vfloat4*)x, freq, amp, time_p, (vfloat4*)out, H);
    }
}